// Round 1
// baseline (69.280 us; speedup 1.0000x reference)
//
#include <hip/hip_runtime.h>
#include <cfloat>

// Problem constants (from reference): N=2048, D=1024, K=256 centroids, NG=512 groups.
#define NROWS 2048
#define DDIM  1024
#define KCEN  256

// One block per row, 256 threads; each thread handles 4 scalars = 2 rotation pairs.
__global__ __launch_bounds__(256)
void planar_quant_kernel(const float* __restrict__ x,
                         const float* __restrict__ cen,   // [256] sorted
                         const float* __restrict__ rot,   // [512*2] = (cos,sin) per group
                         float* __restrict__ out_xhat,    // [N*D]
                         float* __restrict__ out_idx)     // [N*D] as float values
{
    __shared__ float s_cen[KCEN];
    __shared__ float s_mid[KCEN];   // s_mid[255] = +inf pad
    __shared__ float s_red[4];
    __shared__ float s_norm;

    const int row = blockIdx.x;
    const int t   = threadIdx.x;

    // Stage centroids + decision midpoints in LDS (256 threads == 256 centroids).
    s_cen[t] = cen[t];
    __syncthreads();
    s_mid[t] = (t < KCEN - 1) ? 0.5f * (s_cen[t] + s_cen[t + 1]) : FLT_MAX;

    // Coalesced vector loads: x elems [4t..4t+3], rot pairs for groups 2t, 2t+1.
    const float4 xv = *(const float4*)(x + (size_t)row * DDIM + 4 * t);
    const float4 rv = *(const float4*)(rot + 4 * t);   // (c0,s0,c1,s1)

    // Row norm: per-thread sum of squares -> wave shuffle reduce -> cross-wave LDS.
    float ss = xv.x * xv.x + xv.y * xv.y + xv.z * xv.z + xv.w * xv.w;
    #pragma unroll
    for (int off = 32; off >= 1; off >>= 1)
        ss += __shfl_xor(ss, off, 64);
    if ((t & 63) == 0) s_red[t >> 6] = ss;
    __syncthreads();
    if (t == 0) {
        float tot = s_red[0] + s_red[1] + s_red[2] + s_red[3];
        s_norm = fmaxf(sqrtf(tot), 1e-8f);
    }
    __syncthreads();
    const float nrm = s_norm;
    const float inv = 1.0f / nrm;

    // Rotate each pair, quantize each scalar (lower-bound over midpoints + distance
    // fix-up to match argmin-first-index tie semantics), inverse-rotate, rescale.
    float v0 = xv.x * inv, v1 = xv.y * inv, v2 = xv.z * inv, v3 = xv.w * inv;

    float r[4];
    r[0] = rv.x * v0 - rv.y * v1;   // c0*v0 - s0*v1
    r[1] = rv.y * v0 + rv.x * v1;   // s0*v0 + c0*v1
    r[2] = rv.z * v2 - rv.w * v3;
    r[3] = rv.w * v2 + rv.z * v3;

    int   qi[4];
    float qv[4];
    #pragma unroll
    for (int e = 0; e < 4; ++e) {
        const float v = r[e];
        int idx = 0;
        #pragma unroll
        for (int step = 128; step >= 1; step >>= 1) {
            if (s_mid[idx + step - 1] < v) idx += step;
        }
        // Neighbor fix-up with exact distances (argmin picks lowest index on ties).
        float best = fabsf(v - s_cen[idx]);
        if (idx > 0 && fabsf(v - s_cen[idx - 1]) <= best) {
            idx -= 1;
        } else if (idx < KCEN - 1 && fabsf(v - s_cen[idx + 1]) < best) {
            idx += 1;
        }
        qi[e] = idx;
        qv[e] = s_cen[idx];
    }

    // Inverse rotation + rescale.
    float4 xh;
    xh.x = ( rv.x * qv[0] + rv.y * qv[1]) * nrm;   //  c*q0 + s*q1
    xh.y = (-rv.y * qv[0] + rv.x * qv[1]) * nrm;   // -s*q0 + c*q1
    xh.z = ( rv.z * qv[2] + rv.w * qv[3]) * nrm;
    xh.w = (-rv.w * qv[2] + rv.z * qv[3]) * nrm;

    float4 fi;
    fi.x = (float)qi[0]; fi.y = (float)qi[1]; fi.z = (float)qi[2]; fi.w = (float)qi[3];

    const size_t off = (size_t)row * DDIM + 4 * t;
    *(float4*)(out_xhat + off) = xh;
    *(float4*)(out_idx  + off) = fi;
}

extern "C" void kernel_launch(void* const* d_in, const int* in_sizes, int n_in,
                              void* d_out, int out_size, void* d_ws, size_t ws_size,
                              hipStream_t stream) {
    const float* x   = (const float*)d_in[0];   // [2048*1024]
    const float* cen = (const float*)d_in[1];   // [256]
    const float* rot = (const float*)d_in[2];   // [1024]
    float* out       = (float*)d_out;           // [2 * 2048*1024]

    planar_quant_kernel<<<NROWS, 256, 0, stream>>>(
        x, cen, rot, out, out + (size_t)NROWS * DDIM);
}